// Round 3
// baseline (299.592 us; speedup 1.0000x reference)
//
#include <hip/hip_runtime.h>
#include <hip/hip_bf16.h>

#define NN 100000    // nodes
#define NE 1600000   // edges
#define FF 64        // features
#define NC 10        // classes
#define NL 4         // layers
#define NB 128       // graphs
#define LDST 72      // LDS row stride in bf16 elems (144 B)
#define CAP 48       // fixed CSR capacity per node
#define NW 196       // windows of 512 nodes (win = node >> 9)
#define WCAPE 8704   // per-window edge capacity
#define BINB_BLOCKS ((NE + 8191) / 8192)       // 196 (8192 edges/block)
#define XF_BLOCKS (NN * FF / 2048)             // 3125 (8 elems/thread)
#define CONV_BLOCKS (2 * NL * FF * FF / 256)   // 128 (1 elem/thread)
#define LAYER_BLOCKS (NN / 32)                 // 3125 (32 nodes/block, exact)

typedef __attribute__((ext_vector_type(8))) short short8;
typedef __attribute__((ext_vector_type(8))) unsigned short ushort8;
typedef __attribute__((ext_vector_type(4))) float f32x4;
typedef __attribute__((ext_vector_type(2))) float f32x2;

static __device__ __forceinline__ unsigned short f2bf(float x) {
  unsigned int u = __float_as_uint(x);
  unsigned int r = (u + 0x7fffu + ((u >> 16) & 1u)) >> 16;
  return (unsigned short)r;
}
static __device__ __forceinline__ float bf2f(unsigned short u) {
  return __uint_as_float(((unsigned int)u) << 16);
}
static __device__ __forceinline__ uint2 pack_f8(const float* a) {
  int w0 = __builtin_amdgcn_cvt_pk_fp8_f32(a[0], a[1], 0, false);
  w0 = __builtin_amdgcn_cvt_pk_fp8_f32(a[2], a[3], w0, true);
  int w1 = __builtin_amdgcn_cvt_pk_fp8_f32(a[4], a[5], 0, false);
  w1 = __builtin_amdgcn_cvt_pk_fp8_f32(a[6], a[7], w1, true);
  return make_uint2((unsigned)w0, (unsigned)w1);
}
// accumulate 8 fp8 values (one uint2) into 4 f32x2 accumulators
static __device__ __forceinline__ void acc8(f32x2* a, uint2 v) {
#if __has_builtin(__builtin_amdgcn_cvt_pk_f32_fp8)
  a[0] += __builtin_amdgcn_cvt_pk_f32_fp8((int)v.x, false);
  a[1] += __builtin_amdgcn_cvt_pk_f32_fp8((int)v.x, true);
  a[2] += __builtin_amdgcn_cvt_pk_f32_fp8((int)v.y, false);
  a[3] += __builtin_amdgcn_cvt_pk_f32_fp8((int)v.y, true);
#else
  a[0][0] += __builtin_amdgcn_cvt_f32_fp8((int)v.x, 0);
  a[0][1] += __builtin_amdgcn_cvt_f32_fp8((int)v.x, 1);
  a[1][0] += __builtin_amdgcn_cvt_f32_fp8((int)v.x, 2);
  a[1][1] += __builtin_amdgcn_cvt_f32_fp8((int)v.x, 3);
  a[2][0] += __builtin_amdgcn_cvt_f32_fp8((int)v.y, 0);
  a[2][1] += __builtin_amdgcn_cvt_f32_fp8((int)v.y, 1);
  a[3][0] += __builtin_amdgcn_cvt_f32_fp8((int)v.y, 2);
  a[3][1] += __builtin_amdgcn_cvt_f32_fp8((int)v.y, 3);
#endif
}
static __device__ __forceinline__ unsigned char f2f8(float v) {
  return (unsigned char)(__builtin_amdgcn_cvt_pk_fp8_f32(v, v, 0, false) & 0xff);
}

// ============ prep: x->fp8 | W->Wt | zero wcnt + fp8 pad rows + xr ============
__global__ __launch_bounds__(256) void prep_kernel(
    const float* __restrict__ x, const float* __restrict__ W1s,
    const float* __restrict__ W2s, uint2* __restrict__ xf8,
    unsigned short* __restrict__ Wt, int* __restrict__ wcnt,
    uint2* __restrict__ hf8a, uint2* __restrict__ hf8b,
    float* __restrict__ xr) {
  int b = blockIdx.x;
  if (b < XF_BLOCKS) {
    int t = b * 256 + threadIdx.x;
    size_t base = (size_t)t * 8;
    float4 a = *(const float4*)(x + base);
    float4 c = *(const float4*)(x + base + 4);
    float f[8] = {a.x, a.y, a.z, a.w, c.x, c.y, c.z, c.w};
    xf8[t] = pack_f8(f);
  } else if (b < XF_BLOCKS + CONV_BLOCKS) {
    int t = (b - XF_BLOCKS) * 256 + threadIdx.x;   // 32768 threads, 1 elem each
    int mat = t >> 12, idx = t & 4095;
    int k = idx >> 6, n = idx & 63;
    int l = mat >> 1;
    const float* W = (mat & 1) ? (W2s + (size_t)l * FF * FF) : (W1s + (size_t)l * FF * FF);
    Wt[(size_t)mat * FF * FF + n * FF + k] = f2bf(W[k * FF + n]);
  } else {
    int c = threadIdx.x;
    float4 z = make_float4(0.f, 0.f, 0.f, 0.f);
    #pragma unroll
    for (int k = 0; k < 8; ++k)
      *(float4*)(xr + c * 32 + k * 4) = z;   // zero xr (8192 floats)
    if (c < NW) wcnt[c] = 0;
    if (c < 8) {
      xf8[(size_t)NN * 8 + c] = make_uint2(0, 0);
      hf8a[(size_t)NN * 8 + c] = make_uint2(0, 0);
      hf8b[(size_t)NN * 8 + c] = make_uint2(0, 0);
    }
  }
}

// ============ phase 1: bin edges into 196 window regions (LDS multisplit) ============
__global__ __launch_bounds__(1024) void binB_kernel(const int* __restrict__ src,
                                                    const int* __restrict__ dst,
                                                    int* __restrict__ wcnt,
                                                    unsigned int* __restrict__ ebuf) {
  __shared__ int lcnt[NW];
  __shared__ int lbase[NW];
  int t = threadIdx.x;
  int base = blockIdx.x * 8192 + t * 8;
  int d[8], s[8], wj[8];
  bool v[8];
  if (base + 8 <= NE) {
    *(int4*)(&d[0]) = *(const int4*)(dst + base);
    *(int4*)(&d[4]) = *(const int4*)(dst + base + 4);
    *(int4*)(&s[0]) = *(const int4*)(src + base);
    *(int4*)(&s[4]) = *(const int4*)(src + base + 4);
    #pragma unroll
    for (int j = 0; j < 8; ++j) v[j] = true;
  } else {
    #pragma unroll
    for (int j = 0; j < 8; ++j) {
      int e = base + j;
      v[j] = (e < NE);
      d[j] = v[j] ? dst[e] : 0;
      s[j] = v[j] ? src[e] : 0;
    }
  }
  #pragma unroll
  for (int j = 0; j < 8; ++j) wj[j] = d[j] >> 9;
  if (t < NW) lcnt[t] = 0;
  __syncthreads();
  #pragma unroll
  for (int j = 0; j < 8; ++j)
    if (v[j]) atomicAdd(&lcnt[wj[j]], 1);
  __syncthreads();
  if (t < NW) {
    lbase[t] = atomicAdd(&wcnt[t], lcnt[t]);
    lcnt[t] = 0;
  }
  __syncthreads();
  #pragma unroll
  for (int j = 0; j < 8; ++j) {
    if (v[j]) {
      int pos = lbase[wj[j]] + atomicAdd(&lcnt[wj[j]], 1);
      if (pos < WCAPE)
        ebuf[(size_t)wj[j] * WCAPE + pos] =
            ((unsigned)(d[j] & 511) << 17) | (unsigned)s[j];
    }
  }
}

// ============ phase 2: one block per window; LDS cursors; csr + pad + deg ============
__global__ __launch_bounds__(1024) void fillC_kernel(const unsigned int* __restrict__ ebuf,
                                                     const int* __restrict__ wcnt,
                                                     int* __restrict__ csr,
                                                     int* __restrict__ deg) {
  __shared__ int cur[512];
  int b = blockIdx.x;
  int t = threadIdx.x;
  int n0 = b << 9;
  if (t < 512) cur[t] = 0;
  __syncthreads();
  int cnt = min(wcnt[b], WCAPE);
  const unsigned int* ep = ebuf + (size_t)b * WCAPE;
  for (int i = t; i < cnt; i += 1024) {
    unsigned int e = ep[i];
    int dl = e >> 17;
    int s = (int)(e & 0x1ffffu);
    int slot = atomicAdd(&cur[dl], 1);
    if (slot < CAP) csr[(n0 + dl) * CAP + slot] = s;
  }
  __syncthreads();
  if (t < 512) {
    int node = n0 + t;
    if (node < NN) {
      int c = min(cur[t], CAP);
      deg[node] = c;
      int end = (c + 3) & ~3;
      for (; c < end; ++c) csr[node * CAP + c] = NN;
    }
  }
}

// ============ fused layer: out = sig(sig((self + sum nbrs) @ W1) @ W2) ============
// 256 thr = 4 waves, 32 REAL nodes/block (NN = 3125*32 exactly -> no bounds checks).
// Each wave: 8 nodes, 8 lanes/node, 8-B uint2 quarters, ONE pass, 8-deep unroll
// (16 VGPR in flight -> total VGPR stays <=64, 8 waves/SIMD; R2's 88-VGPR version
// halved occupancy to 4 waves/SIMD and regressed 30%).
// Serial gather rounds: ceil(maxdeg-of-8/8) ~ 3 vs ~6 before.
// MFMA: wave-private 16-row LDS region, rows 0-7 real, rows 8-15 garbage
// (GEMM is row-independent; garbage rows never stored). NO barriers anywhere.
// last=0: write fp8 hout8.  last=1: fused global_add_pool -> atomicAdd into xr.
__global__ __launch_bounds__(256) void layer_kernel(
    const uint2* __restrict__ hin8, const int* __restrict__ csr,
    const int* __restrict__ deg, const unsigned short* __restrict__ Wt,
    uint2* __restrict__ hout8, const int* __restrict__ batch,
    float* __restrict__ xr, int last) {
  __shared__ __align__(16) unsigned short uL[64 * LDST];   // 4 waves x 16 rows
  __shared__ __align__(16) unsigned char fb[64 * 64];      // 4096 B fp8 bounce
  int t = threadIdx.x;
  int row0 = blockIdx.x * 32;
  int lane = t & 63, w = t >> 6;
  int j3 = lane & 7;          // 8-byte feature octet
  int gnode = lane >> 3;      // node slot 0..7

  {
    int r = w * 16 + gnode;           // LDS row (wave-private region)
    int node = row0 + w * 8 + gnode;  // always < NN (exact grid)
    f32x2 a[4] = {{0.f, 0.f}, {0.f, 0.f}, {0.f, 0.f}, {0.f, 0.f}};
    const uint2* hp = hin8 + j3;
    acc8(a, hp[(size_t)node * 8]);   // self term (fp8)
    int i = node * CAP;
    int dg = deg[node];
    int endp = i + ((dg + 3) & ~3);
    for (; i + 8 <= endp; i += 8) {   // 8 neighbors in flight (16 VGPR payload)
      int4 x0 = *(const int4*)(csr + i);
      int4 x1 = *(const int4*)(csr + i + 4);
      uint2 r0 = hp[(size_t)x0.x * 8];
      uint2 r1 = hp[(size_t)x0.y * 8];
      uint2 r2 = hp[(size_t)x0.z * 8];
      uint2 r3 = hp[(size_t)x0.w * 8];
      uint2 r4 = hp[(size_t)x1.x * 8];
      uint2 r5 = hp[(size_t)x1.y * 8];
      uint2 r6 = hp[(size_t)x1.z * 8];
      uint2 r7 = hp[(size_t)x1.w * 8];
      acc8(a, r0); acc8(a, r1); acc8(a, r2); acc8(a, r3);
      acc8(a, r4); acc8(a, r5); acc8(a, r6); acc8(a, r7);
    }
    if (i < endp) {   // one remaining group of 4 (segments padded to x4)
      int4 x0 = *(const int4*)(csr + i);
      uint2 r0 = hp[(size_t)x0.x * 8];
      uint2 r1 = hp[(size_t)x0.y * 8];
      uint2 r2 = hp[(size_t)x0.z * 8];
      uint2 r3 = hp[(size_t)x0.w * 8];
      acc8(a, r0); acc8(a, r1); acc8(a, r2); acc8(a, r3);
    }
    ushort8 u;
    #pragma unroll
    for (int kk = 0; kk < 8; ++kk) u[kk] = f2bf(a[kk >> 1][kk & 1]);
    *(ushort8*)(&uL[r * LDST + j3 * 8]) = u;
  }

  __builtin_amdgcn_sched_barrier(0);   // keep weight loads out of gather live range

  int m = lane & 15, q = lane >> 4;
  short8 b1[4][2], b2[4][2];
  #pragma unroll
  for (int c4 = 0; c4 < 4; ++c4) {
    #pragma unroll
    for (int s = 0; s < 2; ++s) {
      b1[c4][s] = *(const short8*)(Wt + (c4 * 16 + m) * FF + s * 32 + q * 8);
      b2[c4][s] = *(const short8*)(Wt + FF * FF + (c4 * 16 + m) * FF + s * 32 + q * 8);
    }
  }

  // GEMM1 -> back into uL (wave-private; rows 8-15 are garbage, harmless)
  f32x4 acc[4] = {{0,0,0,0},{0,0,0,0},{0,0,0,0},{0,0,0,0}};
  #pragma unroll
  for (int s = 0; s < 2; ++s) {
    short8 a = *(const short8*)(&uL[(w * 16 + m) * LDST + s * 32 + q * 8]);
    #pragma unroll
    for (int c4 = 0; c4 < 4; ++c4)
      acc[c4] = __builtin_amdgcn_mfma_f32_16x16x32_bf16(a, b1[c4][s], acc[c4], 0, 0, 0);
  }
  #pragma unroll
  for (int c4 = 0; c4 < 4; ++c4) {
    #pragma unroll
    for (int i = 0; i < 4; ++i) {
      int r = w * 16 + q * 4 + i;     // C/D: row = q*4+reg, col = c4*16+m
      float sgv = 1.f / (1.f + __expf(-acc[c4][i]));
      uL[r * LDST + c4 * 16 + m] = f2bf(sgv);
    }
  }

  // GEMM2
  f32x4 acc2[4] = {{0,0,0,0},{0,0,0,0},{0,0,0,0},{0,0,0,0}};
  #pragma unroll
  for (int s = 0; s < 2; ++s) {
    short8 a = *(const short8*)(&uL[(w * 16 + m) * LDST + s * 32 + q * 8]);
    #pragma unroll
    for (int c4 = 0; c4 < 4; ++c4)
      acc2[c4] = __builtin_amdgcn_mfma_f32_16x16x32_bf16(a, b2[c4][s], acc2[c4], 0, 0, 0);
  }
  if (last) {
    // write sigmoid rows into wave-private uL, then run-length pool this wave's
    // own 8 real rows (batch sorted) with one atomic per boundary per lane
    #pragma unroll
    for (int c4 = 0; c4 < 4; ++c4) {
      #pragma unroll
      for (int i = 0; i < 4; ++i) {
        int r = w * 16 + q * 4 + i;
        float sgv = 1.f / (1.f + __expf(-acc2[c4][i]));
        uL[r * LDST + c4 * 16 + m] = f2bf(sgv);
      }
    }
    int node0 = row0 + w * 8;
    {
      float pacc = 0.f;
      int cur = batch[node0];
      #pragma unroll
      for (int r = 0; r < 8; ++r) {
        int node = node0 + r;
        int bb = batch[node];
        if (bb != cur) {
          unsafeAtomicAdd(&xr[(size_t)cur * FF + lane], pacc);
          pacc = 0.f; cur = bb;
        }
        pacc += bf2f(uL[(w * 16 + r) * LDST + lane]);
      }
      unsafeAtomicAdd(&xr[(size_t)cur * FF + lane], pacc);
    }
  } else {
    #pragma unroll
    for (int c4 = 0; c4 < 4; ++c4) {
      #pragma unroll
      for (int i = 0; i < 4; ++i) {
        int r = w * 16 + q * 4 + i;   // wave-private rows in fb
        float sgv = 1.f / (1.f + __expf(-acc2[c4][i]));
        fb[r * 64 + c4 * 16 + m] = f2f8(sgv);
      }
    }
    {
      int r = w * 16 + gnode;           // real rows only (0..7 of region)
      int node = row0 + w * 8 + gnode;
      uint2 v = *(const uint2*)(fb + r * 64 + j3 * 8);
      hout8[(size_t)node * 8 + j3] = v;
    }
  }
}

// ============ head: logits + log_softmax from finished xr ============
__global__ __launch_bounds__(64) void head_kernel(
    const float* __restrict__ xr, const float* __restrict__ fcw,
    const float* __restrict__ fcb, float* __restrict__ out) {
  int b = blockIdx.x, lane = threadIdx.x;
  float v = xr[(size_t)b * FF + lane];
  out[NB * NC + (size_t)b * FF + lane] = v;    // output 1: xr
  float logit[NC];
  #pragma unroll
  for (int c = 0; c < NC; ++c) {
    float s = v * fcw[c * FF + lane];
    #pragma unroll
    for (int o = 32; o > 0; o >>= 1) s += __shfl_xor(s, o, 64);
    logit[c] = s + fcb[c];
  }
  float mx = logit[0];
  #pragma unroll
  for (int c = 1; c < NC; ++c) mx = fmaxf(mx, logit[c]);
  float se = 0.f;
  #pragma unroll
  for (int c = 0; c < NC; ++c) se += expf(logit[c] - mx);
  float lse = logf(se);
  if (lane < NC) out[b * NC + lane] = logit[lane] - mx - lse;
}

extern "C" void kernel_launch(void* const* d_in, const int* in_sizes, int n_in,
                              void* d_out, int out_size, void* d_ws, size_t ws_size,
                              hipStream_t stream) {
  const float* x     = (const float*)d_in[0];
  const int*   ei    = (const int*)d_in[1];
  const int*   batch = (const int*)d_in[2];
  const float* W1s   = (const float*)d_in[3];
  const float* W2s   = (const float*)d_in[4];
  const float* fcw   = (const float*)d_in[5];
  const float* fcb   = (const float*)d_in[6];
  float* out = (float*)d_out;

  char* p = (char*)d_ws;
  uint2* xf8  = (uint2*)p; p += (size_t)(NN + 1) * 8 * 8;                    // 6.4 MB
  uint2* hf8a = (uint2*)p; p += (size_t)(NN + 1) * 8 * 8;                    // 6.4 MB
  uint2* hf8b = (uint2*)p; p += (size_t)(NN + 1) * 8 * 8;                    // 6.4 MB
  int* csr    = (int*)p;   p += (size_t)NN * CAP * 4;                        // 19.2 MB
  unsigned int* ebuf = (unsigned int*)p; p += (size_t)NW * WCAPE * 4;        // 6.8 MB
  int* deg    = (int*)p;   p += (size_t)NN * 4;                              // 0.4 MB
  int* wcnt   = (int*)p;   p += (size_t)((NW + 63) & ~63) * 4;
  float* xr   = (float*)p; p += (size_t)NB * FF * 4;
  unsigned short* Wtall = (unsigned short*)p; p += (size_t)2 * NL * FF * FF * 2;

  const int* src = ei;
  const int* dst = ei + NE;

  // 1) prep: x->fp8, weights->Wt, zero wcnt/fp8 pad rows/xr
  prep_kernel<<<XF_BLOCKS + CONV_BLOCKS + 1, 256, 0, stream>>>(
      x, W1s, W2s, xf8, Wtall, wcnt, hf8a, hf8b, xr);

  // 2) bin edges into window regions; 3) per-window csr fill + pad + deg
  binB_kernel<<<BINB_BLOCKS, 1024, 0, stream>>>(src, dst, wcnt, ebuf);
  fillC_kernel<<<NW, 1024, 0, stream>>>(ebuf, wcnt, csr, deg);

  // 4-7) layers: fp8-only chain; last layer fuses global_add_pool into epilogue
  const uint2* chain_in[NL]  = {xf8, hf8a, hf8b, hf8a};
  uint2*       chain_out[NL] = {hf8a, hf8b, hf8a, hf8b};  // last unused
  for (int l = 0; l < NL; ++l) {
    int last = (l == NL - 1) ? 1 : 0;
    layer_kernel<<<LAYER_BLOCKS, 256, 0, stream>>>(chain_in[l], csr, deg,
        Wtall + (size_t)l * 2 * FF * FF, chain_out[l], batch, xr, last);
  }

  // 8) head
  head_kernel<<<NB, 64, 0, stream>>>(xr, fcw, fcb, out);
}

// Round 4
// 266.106 us; speedup vs baseline: 1.1258x; 1.1258x over previous
//
#include <hip/hip_runtime.h>
#include <hip/hip_bf16.h>

#define NN 100000    // nodes
#define NE 1600000   // edges
#define FF 64        // features
#define NC 10        // classes
#define NL 4         // layers
#define NB 128       // graphs
#define LDST 72      // LDS row stride in bf16 elems (144 B)
#define CAP 48       // fixed CSR capacity per node
#define NW 196       // windows of 512 nodes (win = node >> 9)
#define WCAPE 8704   // per-window edge capacity
#define PB_BIN 196                              // binB blocks (8192 edges each)
#define PB_XF 782                               // x->fp8 blocks (1024 thr, 8 elems)
#define PB_W 32                                 // weight-transpose blocks
#define PB_TOTAL (PB_BIN + PB_XF + PB_W + 1)    // 1011

typedef __attribute__((ext_vector_type(8))) short short8;
typedef __attribute__((ext_vector_type(8))) unsigned short ushort8;
typedef __attribute__((ext_vector_type(4))) float f32x4;
typedef __attribute__((ext_vector_type(2))) float f32x2;

static __device__ __forceinline__ unsigned short f2bf(float x) {
  unsigned int u = __float_as_uint(x);
  unsigned int r = (u + 0x7fffu + ((u >> 16) & 1u)) >> 16;
  return (unsigned short)r;
}
static __device__ __forceinline__ float bf2f(unsigned short u) {
  return __uint_as_float(((unsigned int)u) << 16);
}
static __device__ __forceinline__ uint2 pack_f8(const float* a) {
  int w0 = __builtin_amdgcn_cvt_pk_fp8_f32(a[0], a[1], 0, false);
  w0 = __builtin_amdgcn_cvt_pk_fp8_f32(a[2], a[3], w0, true);
  int w1 = __builtin_amdgcn_cvt_pk_fp8_f32(a[4], a[5], 0, false);
  w1 = __builtin_amdgcn_cvt_pk_fp8_f32(a[6], a[7], w1, true);
  return make_uint2((unsigned)w0, (unsigned)w1);
}
// accumulate 8 fp8 values (one 8-byte word pair) into 4 f32x2 accumulators
static __device__ __forceinline__ void acc8w(f32x2* a, unsigned int x,
                                             unsigned int y) {
#if __has_builtin(__builtin_amdgcn_cvt_pk_f32_fp8)
  a[0] += __builtin_amdgcn_cvt_pk_f32_fp8((int)x, false);
  a[1] += __builtin_amdgcn_cvt_pk_f32_fp8((int)x, true);
  a[2] += __builtin_amdgcn_cvt_pk_f32_fp8((int)y, false);
  a[3] += __builtin_amdgcn_cvt_pk_f32_fp8((int)y, true);
#else
  a[0][0] += __builtin_amdgcn_cvt_f32_fp8((int)x, 0);
  a[0][1] += __builtin_amdgcn_cvt_f32_fp8((int)x, 1);
  a[1][0] += __builtin_amdgcn_cvt_f32_fp8((int)x, 2);
  a[1][1] += __builtin_amdgcn_cvt_f32_fp8((int)x, 3);
  a[2][0] += __builtin_amdgcn_cvt_f32_fp8((int)y, 0);
  a[2][1] += __builtin_amdgcn_cvt_f32_fp8((int)y, 1);
  a[3][0] += __builtin_amdgcn_cvt_f32_fp8((int)y, 2);
  a[3][1] += __builtin_amdgcn_cvt_f32_fp8((int)y, 3);
#endif
}
// accumulate a 16-byte fp8 quarter-row into 8 f32x2 accumulators
static __device__ __forceinline__ void acc16(f32x2* a, uint4 v) {
  acc8w(a, v.x, v.y);
  acc8w(a + 4, v.z, v.w);
}
static __device__ __forceinline__ unsigned char f2f8(float v) {
  return (unsigned char)(__builtin_amdgcn_cvt_pk_fp8_f32(v, v, 0, false) & 0xff);
}

// ============ fused prep + edge binning ============
// Blocks 0..195: bin 8192 edges each into window regions (LDS multisplit).
// Blocks 196..977: x->fp8. Blocks 978..1009: W->Wt. Block 1010: fp8 pad rows.
// binB alone uses 196 of 256 CUs; the conversion blocks fill the idle CUs and
// one kernel-launch gap disappears. wcnt+xr are zeroed by hipMemsetAsync.
__global__ __launch_bounds__(1024) void prepbin_kernel(
    const float* __restrict__ x, const int* __restrict__ src,
    const int* __restrict__ dst, const float* __restrict__ W1s,
    const float* __restrict__ W2s, uint2* __restrict__ xf8,
    unsigned short* __restrict__ Wt, int* __restrict__ wcnt,
    unsigned int* __restrict__ ebuf, uint2* __restrict__ hf8a,
    uint2* __restrict__ hf8b) {
  __shared__ int lcnt[NW];
  __shared__ int lbase[NW];
  int b = blockIdx.x;
  int t = threadIdx.x;
  if (b < PB_BIN) {
    int base = b * 8192 + t * 8;
    int d[8], s[8], wj[8];
    bool v[8];
    if (base + 8 <= NE) {
      *(int4*)(&d[0]) = *(const int4*)(dst + base);
      *(int4*)(&d[4]) = *(const int4*)(dst + base + 4);
      *(int4*)(&s[0]) = *(const int4*)(src + base);
      *(int4*)(&s[4]) = *(const int4*)(src + base + 4);
      #pragma unroll
      for (int j = 0; j < 8; ++j) v[j] = true;
    } else {
      #pragma unroll
      for (int j = 0; j < 8; ++j) {
        int e = base + j;
        v[j] = (e < NE);
        d[j] = v[j] ? dst[e] : 0;
        s[j] = v[j] ? src[e] : 0;
      }
    }
    #pragma unroll
    for (int j = 0; j < 8; ++j) wj[j] = d[j] >> 9;
    if (t < NW) lcnt[t] = 0;
    __syncthreads();
    #pragma unroll
    for (int j = 0; j < 8; ++j)
      if (v[j]) atomicAdd(&lcnt[wj[j]], 1);
    __syncthreads();
    if (t < NW) {
      lbase[t] = atomicAdd(&wcnt[t], lcnt[t]);
      lcnt[t] = 0;
    }
    __syncthreads();
    #pragma unroll
    for (int j = 0; j < 8; ++j) {
      if (v[j]) {
        int pos = lbase[wj[j]] + atomicAdd(&lcnt[wj[j]], 1);
        if (pos < WCAPE)
          ebuf[(size_t)wj[j] * WCAPE + pos] =
              ((unsigned)(d[j] & 511) << 17) | (unsigned)s[j];
      }
    }
  } else if (b < PB_BIN + PB_XF) {
    int g = (b - PB_BIN) * 1024 + t;
    if (g < NN * FF / 8) {
      size_t base = (size_t)g * 8;
      float4 a = *(const float4*)(x + base);
      float4 c = *(const float4*)(x + base + 4);
      float f[8] = {a.x, a.y, a.z, a.w, c.x, c.y, c.z, c.w};
      xf8[g] = pack_f8(f);
    }
  } else if (b < PB_BIN + PB_XF + PB_W) {
    int g = (b - PB_BIN - PB_XF) * 1024 + t;   // 32768 threads, 1 elem each
    int mat = g >> 12, idx = g & 4095;
    int k = idx >> 6, n = idx & 63;
    int l = mat >> 1;
    const float* W = (mat & 1) ? (W2s + (size_t)l * FF * FF) : (W1s + (size_t)l * FF * FF);
    Wt[(size_t)mat * FF * FF + n * FF + k] = f2bf(W[k * FF + n]);
  } else {
    if (t < 8) {
      xf8[(size_t)NN * 8 + t] = make_uint2(0, 0);
      hf8a[(size_t)NN * 8 + t] = make_uint2(0, 0);
      hf8b[(size_t)NN * 8 + t] = make_uint2(0, 0);
    }
  }
}

// ============ phase 2: one block per window; LDS cursors; csr + pad + deg ============
__global__ __launch_bounds__(1024) void fillC_kernel(const unsigned int* __restrict__ ebuf,
                                                     const int* __restrict__ wcnt,
                                                     int* __restrict__ csr,
                                                     int* __restrict__ deg) {
  __shared__ int cur[512];
  int b = blockIdx.x;
  int t = threadIdx.x;
  int n0 = b << 9;
  if (t < 512) cur[t] = 0;
  __syncthreads();
  int cnt = min(wcnt[b], WCAPE);
  const unsigned int* ep = ebuf + (size_t)b * WCAPE;
  for (int i = t; i < cnt; i += 1024) {
    unsigned int e = ep[i];
    int dl = e >> 17;
    int s = (int)(e & 0x1ffffu);
    int slot = atomicAdd(&cur[dl], 1);
    if (slot < CAP) csr[(n0 + dl) * CAP + slot] = s;
  }
  __syncthreads();
  if (t < 512) {
    int node = n0 + t;
    if (node < NN) {
      int c = min(cur[t], CAP);
      deg[node] = c;
      int end = (c + 3) & ~3;
      for (; c < end; ++c) csr[node * CAP + c] = NN;
    }
  }
}

// ============ fused layer: out = sig(sig((self + sum nbrs) @ W1) @ W2) ============
// R1 structure (measured 44.2 us, VGPR 56): 256 thr = 4 waves, 64 rows/block,
// wave-private uL rows, NO barriers. Gather: 4 lanes/node x 16-B uint4
// quarters, 16 nodes/wave, ONE pass, depth-4. Occupancy-optimal: VGPR <= 64
// (R2's 88-VGPR depth-8 halved occupancy, -30%); 16 nodes/wave amortizes the
// per-wave fixed cost (weights 16 KB/wave + 2 GEMMs; R3's 8 nodes/wave, +21%).
// last=0: write fp8 hout8.  last=1: fused global_add_pool -> atomicAdd into xr.
__global__ __launch_bounds__(256) void layer_kernel(
    const uint2* __restrict__ hin8, const int* __restrict__ csr,
    const int* __restrict__ deg, const unsigned short* __restrict__ Wt,
    uint2* __restrict__ hout8, const int* __restrict__ batch,
    float* __restrict__ xr, int last) {
  __shared__ __align__(16) unsigned short uL[64 * LDST];   // 9216 B
  __shared__ __align__(16) unsigned char fb[64 * 64];      // 4096 B fp8 bounce
  int t = threadIdx.x;
  int row0 = blockIdx.x * 64;
  int lane = t & 63, w = t >> 6;
  int j2 = lane & 3;          // 16-byte feature quarter
  int gnode = lane >> 2;      // node slot 0..15

  {
    int r = w * 16 + gnode;
    int node = row0 + r;
    f32x2 a[8] = {{0.f,0.f},{0.f,0.f},{0.f,0.f},{0.f,0.f},
                  {0.f,0.f},{0.f,0.f},{0.f,0.f},{0.f,0.f}};
    const uint4* hp4 = (const uint4*)hin8 + j2;
    if (node < NN) {
      acc16(a, hp4[(size_t)node * 4]);   // self term (fp8)
      int i = node * CAP;
      int dg = deg[node];
      int endp = i + ((dg + 3) & ~3);
      for (; i < endp; i += 4) {   // segments padded to x4 with sentinel NN
        int4 x0 = *(const int4*)(csr + i);
        uint4 r0 = hp4[(size_t)x0.x * 4];
        uint4 r1 = hp4[(size_t)x0.y * 4];
        uint4 r2 = hp4[(size_t)x0.z * 4];
        uint4 r3 = hp4[(size_t)x0.w * 4];
        acc16(a, r0); acc16(a, r1); acc16(a, r2); acc16(a, r3);
      }
    }
    ushort8 u0, u1;
    #pragma unroll
    for (int kk = 0; kk < 8; ++kk) u0[kk] = f2bf(a[kk >> 1][kk & 1]);
    #pragma unroll
    for (int kk = 0; kk < 8; ++kk) u1[kk] = f2bf(a[4 + (kk >> 1)][kk & 1]);
    *(ushort8*)(&uL[r * LDST + j2 * 16]) = u0;
    *(ushort8*)(&uL[r * LDST + j2 * 16 + 8]) = u1;
  }

  __builtin_amdgcn_sched_barrier(0);   // keep weight loads out of gather live range

  int m = lane & 15, q = lane >> 4;
  short8 b1[4][2], b2[4][2];
  #pragma unroll
  for (int c4 = 0; c4 < 4; ++c4) {
    #pragma unroll
    for (int s = 0; s < 2; ++s) {
      b1[c4][s] = *(const short8*)(Wt + (c4 * 16 + m) * FF + s * 32 + q * 8);
      b2[c4][s] = *(const short8*)(Wt + FF * FF + (c4 * 16 + m) * FF + s * 32 + q * 8);
    }
  }

  // GEMM1 -> back into uL (wave-private; no barrier)
  f32x4 acc[4] = {{0,0,0,0},{0,0,0,0},{0,0,0,0},{0,0,0,0}};
  #pragma unroll
  for (int s = 0; s < 2; ++s) {
    short8 a = *(const short8*)(&uL[(w * 16 + m) * LDST + s * 32 + q * 8]);
    #pragma unroll
    for (int c4 = 0; c4 < 4; ++c4)
      acc[c4] = __builtin_amdgcn_mfma_f32_16x16x32_bf16(a, b1[c4][s], acc[c4], 0, 0, 0);
  }
  #pragma unroll
  for (int c4 = 0; c4 < 4; ++c4) {
    #pragma unroll
    for (int i = 0; i < 4; ++i) {
      int r = w * 16 + q * 4 + i;     // C/D: row = q*4+reg, col = c4*16+m
      float sgv = 1.f / (1.f + __expf(-acc[c4][i]));
      uL[r * LDST + c4 * 16 + m] = f2bf(sgv);
    }
  }

  // GEMM2
  f32x4 acc2[4] = {{0,0,0,0},{0,0,0,0},{0,0,0,0},{0,0,0,0}};
  #pragma unroll
  for (int s = 0; s < 2; ++s) {
    short8 a = *(const short8*)(&uL[(w * 16 + m) * LDST + s * 32 + q * 8]);
    #pragma unroll
    for (int c4 = 0; c4 < 4; ++c4)
      acc2[c4] = __builtin_amdgcn_mfma_f32_16x16x32_bf16(a, b2[c4][s], acc2[c4], 0, 0, 0);
  }
  if (last) {
    // write sigmoid rows into wave-private uL, then run-length pool this wave's
    // own 16 rows (batch sorted) with one atomic per boundary per lane
    #pragma unroll
    for (int c4 = 0; c4 < 4; ++c4) {
      #pragma unroll
      for (int i = 0; i < 4; ++i) {
        int r = w * 16 + q * 4 + i;
        float sgv = 1.f / (1.f + __expf(-acc2[c4][i]));
        uL[r * LDST + c4 * 16 + m] = f2bf(sgv);
      }
    }
    int r0 = w * 16;
    int node0 = row0 + r0;
    if (node0 < NN) {
      float pacc = 0.f;
      int cur = batch[node0];
      #pragma unroll
      for (int r = 0; r < 16; ++r) {
        int node = node0 + r;
        if (node < NN) {
          int bb = batch[node];
          if (bb != cur) {
            unsafeAtomicAdd(&xr[(size_t)cur * FF + lane], pacc);
            pacc = 0.f; cur = bb;
          }
          pacc += bf2f(uL[(r0 + r) * LDST + lane]);
        }
      }
      unsafeAtomicAdd(&xr[(size_t)cur * FF + lane], pacc);
    }
  } else {
    #pragma unroll
    for (int c4 = 0; c4 < 4; ++c4) {
      #pragma unroll
      for (int i = 0; i < 4; ++i) {
        int r = w * 16 + q * 4 + i;   // rows w*16..w*16+15: wave-private in fb
        float sgv = 1.f / (1.f + __expf(-acc2[c4][i]));
        fb[r * 64 + c4 * 16 + m] = f2f8(sgv);
      }
    }
    {
      int r = w * 16 + gnode;
      int node = row0 + r;
      if (node < NN) {
        uint4 v = *(const uint4*)(fb + r * 64 + j2 * 16);
        uint4* hout4 = (uint4*)hout8;
        hout4[(size_t)node * 4 + j2] = v;
      }
    }
  }
}

// ============ head: logits + log_softmax from finished xr ============
__global__ __launch_bounds__(64) void head_kernel(
    const float* __restrict__ xr, const float* __restrict__ fcw,
    const float* __restrict__ fcb, float* __restrict__ out) {
  int b = blockIdx.x, lane = threadIdx.x;
  float v = xr[(size_t)b * FF + lane];
  out[NB * NC + (size_t)b * FF + lane] = v;    // output 1: xr
  float logit[NC];
  #pragma unroll
  for (int c = 0; c < NC; ++c) {
    float s = v * fcw[c * FF + lane];
    #pragma unroll
    for (int o = 32; o > 0; o >>= 1) s += __shfl_xor(s, o, 64);
    logit[c] = s + fcb[c];
  }
  float mx = logit[0];
  #pragma unroll
  for (int c = 1; c < NC; ++c) mx = fmaxf(mx, logit[c]);
  float se = 0.f;
  #pragma unroll
  for (int c = 0; c < NC; ++c) se += expf(logit[c] - mx);
  float lse = logf(se);
  if (lane < NC) out[b * NC + lane] = logit[lane] - mx - lse;
}

extern "C" void kernel_launch(void* const* d_in, const int* in_sizes, int n_in,
                              void* d_out, int out_size, void* d_ws, size_t ws_size,
                              hipStream_t stream) {
  const float* x     = (const float*)d_in[0];
  const int*   ei    = (const int*)d_in[1];
  const int*   batch = (const int*)d_in[2];
  const float* W1s   = (const float*)d_in[3];
  const float* W2s   = (const float*)d_in[4];
  const float* fcw   = (const float*)d_in[5];
  const float* fcb   = (const float*)d_in[6];
  float* out = (float*)d_out;

  char* p = (char*)d_ws;
  uint2* xf8  = (uint2*)p; p += (size_t)(NN + 1) * 8 * 8;                    // 6.4 MB
  uint2* hf8a = (uint2*)p; p += (size_t)(NN + 1) * 8 * 8;                    // 6.4 MB
  uint2* hf8b = (uint2*)p; p += (size_t)(NN + 1) * 8 * 8;                    // 6.4 MB
  int* csr    = (int*)p;   p += (size_t)NN * CAP * 4;                        // 19.2 MB
  unsigned int* ebuf = (unsigned int*)p; p += (size_t)NW * WCAPE * 4;        // 6.8 MB
  int* deg    = (int*)p;   p += (size_t)NN * 4;                              // 0.4 MB
  int* wcnt   = (int*)p;   p += (size_t)((NW + 63) & ~63) * 4;               // 256 B
  float* xr   = (float*)p; p += (size_t)NB * FF * 4;                         // 32 KB
  unsigned short* Wtall = (unsigned short*)p; p += (size_t)2 * NL * FF * FF * 2;

  const int* src = ei;
  const int* dst = ei + NE;

  // 0) zero wcnt + xr in one contiguous stream-ordered memset (capture-safe)
  hipMemsetAsync(wcnt, 0,
                 (size_t)((NW + 63) & ~63) * 4 + (size_t)NB * FF * 4, stream);

  // 1) fused prep + edge binning (conversion blocks fill CUs idle during binB)
  prepbin_kernel<<<PB_TOTAL, 1024, 0, stream>>>(
      x, src, dst, W1s, W2s, xf8, Wtall, wcnt, ebuf, hf8a, hf8b);

  // 2) per-window csr fill + pad + deg
  fillC_kernel<<<NW, 1024, 0, stream>>>(ebuf, wcnt, csr, deg);

  // 3-6) layers: fp8-only chain; last layer fuses global_add_pool into epilogue
  int layer_blocks = (NN + 63) / 64;   // 1563
  const uint2* chain_in[NL]  = {xf8, hf8a, hf8b, hf8a};
  uint2*       chain_out[NL] = {hf8a, hf8b, hf8a, hf8b};  // last unused
  for (int l = 0; l < NL; ++l) {
    int last = (l == NL - 1) ? 1 : 0;
    layer_kernel<<<layer_blocks, 256, 0, stream>>>(chain_in[l], csr, deg,
        Wtall + (size_t)l * 2 * FF * FF, chain_out[l], batch, xr, last);
  }

  // 7) head
  head_kernel<<<NB, 64, 0, stream>>>(xr, fcw, fcb, out);
}